// Round 7
// baseline (147.008 us; speedup 1.0000x reference)
//
#include <hip/hip_runtime.h>
#include <hip/hip_bf16.h>
#include <stdint.h>

typedef float    f32x4 __attribute__((ext_vector_type(4)));
typedef _Float16 f16x4 __attribute__((ext_vector_type(4)));
typedef _Float16 f16x8 __attribute__((ext_vector_type(8)));

#define NSTEPS 15
#define NBLK 256u

__device__ __forceinline__ void gld_lds16(const void* g, void* l) {
  __builtin_amdgcn_global_load_lds(
      (const __attribute__((address_space(1))) uint32_t*)g,
      (__attribute__((address_space(3))) uint32_t*)l, 16, 0, 0);
}

// Device-scope grid barrier. Safe: grid==256, 128KB LDS forces 1 block/CU on
// 256 CUs -> all blocks co-resident. Counters zeroed by init_kernel per call.
__device__ __forceinline__ void gbar(unsigned* c) {
  __syncthreads();
  if (threadIdx.x == 0) {
    __threadfence();
    __hip_atomic_fetch_add(c, 1u, __ATOMIC_ACQ_REL, __HIP_MEMORY_SCOPE_AGENT);
    while (__hip_atomic_load(c, __ATOMIC_ACQUIRE, __HIP_MEMORY_SCOPE_AGENT) < NBLK)
      __builtin_amdgcn_s_sleep(2);
  }
  __syncthreads();
}

__global__ void init_kernel(unsigned* cnt) {
  if (threadIdx.x < 8) cnt[threadIdx.x] = 0u;
}

__global__ __launch_bounds__(512, 2) void mega_kernel(
    const int* __restrict__ x, const float* __restrict__ embed,
    const float* __restrict__ W1, const float* __restrict__ b1,
    const float* __restrict__ W2, const float* __restrict__ b2,
    const float* __restrict__ beta1p, const float* __restrict__ thr1p,
    const float* __restrict__ beta2p,
    _Float16* __restrict__ Ap, _Float16* __restrict__ Btp,
    _Float16* __restrict__ W2T, float* __restrict__ Tp,
    _Float16* __restrict__ S, unsigned* __restrict__ cnt,
    float* __restrict__ out)
{
  __shared__ __align__(16) char lds[131072];
  const int t    = threadIdx.x;
  const int b    = blockIdx.x;
  const int lane = t & 63;
  const int wave = t >> 6;

  // ======================= P0: prep =======================
  {
    // split_e: embed [2048][512] f32 -> Ap [2048][1024] = [e0|e1] (Dekker)
#pragma unroll
    for (int pass = 0; pass < 2; ++pass) {
      const int i  = pass * 131072 + b * 512 + t;
      const int m  = i >> 7;
      const int k4 = (i & 127) * 4;
      f32x4 v = *(const f32x4*)&embed[(size_t)m * 512 + k4];
      f16x4 h0, h1;
#pragma unroll
      for (int j = 0; j < 4; ++j) {
        h0[j] = (_Float16)v[j];
        h1[j] = (_Float16)(v[j] - (float)h0[j]);
      }
      _Float16* r = Ap + (size_t)m * 1024 + k4;
      *(f16x4*)(r)       = h0;
      *(f16x4*)(r + 512) = h1;
    }

    // transposes: blocks 0-63 -> w1t (2 tiles), 64-191 -> w2t (2 tiles)
    auto sh = (_Float16(*)[2][64][72])lds;   // [half][buf][64][72]
    const int half = t >> 8;
    const int tq   = t & 255;
    const int kk   = tq >> 4;
    const int n4   = (tq & 15) * 4;

    if (b < 64) {            // w1t: W1 [1024][512] -> Btp [1024][1024] (T,64x,split)
      const int v  = b * 2 + half;
      const int n0 = (v & 7) * 64;
      const int k0 = ((v >> 3) & 7) * 64;
      const int z  = v >> 6;
#pragma unroll
      for (int i = 0; i < 4; ++i) {
        f32x4 w = *(const f32x4*)&W1[(size_t)(z * 512 + k0 + kk + i * 16) * 512 + n0 + n4];
#pragma unroll
        for (int j = 0; j < 4; ++j) {
          float s = w[j] * 64.0f;             // exact pow2 scale
          _Float16 hi = (_Float16)s;
          sh[half][0][n4 + j][kk + i * 16] = hi;
          sh[half][1][n4 + j][kk + i * 16] = (_Float16)(s - (float)hi);
        }
      }
    } else if (b < 192) {    // w2t: W2 [512][2048] -> W2T [2048][512] (T)
      const int v  = (b - 64) * 2 + half;
      const int n0 = (v & 31) * 64;
      const int k0 = (v >> 5) * 64;
#pragma unroll
      for (int i = 0; i < 4; ++i) {
        f32x4 w = *(const f32x4*)&W2[(size_t)(k0 + kk + i * 16) * 2048 + n0 + n4];
#pragma unroll
        for (int j = 0; j < 4; ++j) sh[half][0][n4 + j][kk + i * 16] = (_Float16)w[j];
      }
    }
    __syncthreads();
    if (b < 64) {
      const int v  = b * 2 + half;
      const int n0 = (v & 7) * 64;
      const int k0 = ((v >> 3) & 7) * 64;
      const int z  = v >> 6;
#pragma unroll
      for (int i = 0; i < 2; ++i) {
        const int nn = (tq >> 3) + i * 32;
        const int k8 = (tq & 7) * 8;
        _Float16* r = Btp + (size_t)(z * 512 + n0 + nn) * 1024 + k0 + k8;
        *(uint4*)(r)       = *(const uint4*)&sh[half][0][nn][k8];
        *(uint4*)(r + 512) = *(const uint4*)&sh[half][1][nn][k8];
      }
    } else if (b < 192) {
      const int v  = (b - 64) * 2 + half;
      const int n0 = (v & 31) * 64;
      const int k0 = (v >> 5) * 64;
#pragma unroll
      for (int i = 0; i < 2; ++i) {
        const int nn = (tq >> 3) + i * 32;
        const int k8 = (tq & 7) * 8;
        *(uint4*)&W2T[(size_t)(n0 + nn) * 512 + k0 + k8] = *(const uint4*)&sh[half][0][nn][k8];
      }
    }
  }
  gbar(cnt + 0);

  // ======================= P1: gemm1 (R5 v1 z-split) =======================
  // Tp[z] = (1/64) * Ap @ Btp^T over virtual K-range [z*768,(z+1)*768)
  // waves 0-3: z=0 virtual block, waves 4-7: z=1. 128x64 tile, FM2/FN4.
  {
    const int z  = wave >> 2;
    const int vw = wave & 3;
    char* AsB = lds + z * 24576;            // 128 rows x 128B
    char* BsB = AsB + 16384;                //  64 rows x 128B

    const int bid = (b & 7) * 32 + (b >> 3);   // XCD swizzle
    const int m0 = (bid >> 4) * 128;
    const int n0 = (bid & 15) * 64;

    f32x4 acc[2][4] = {};

    for (int kt = 0; kt < 12; ++kt) {
      const int vk0  = z * 768 + kt * 64;
      const int acol = (vk0 < 1024) ? vk0 : vk0 - 1024;
      const int bcol = (vk0 < 1024) ? (vk0 & 511) : vk0 - 512;
#pragma unroll
      for (int i = 0; i < 4; ++i) {        // A: 16KB
        const int ob  = i * 4096 + vw * 1024;
        const int o   = ob + lane * 16;
        const int row = o >> 7;
        const int c   = ((o >> 4) & 7) ^ (row & 7);
        gld_lds16(Ap + ((size_t)(m0 + row) * 1024 + acol + c * 8), AsB + ob);
      }
#pragma unroll
      for (int i = 0; i < 2; ++i) {        // B: 8KB
        const int ob  = i * 4096 + vw * 1024;
        const int o   = ob + lane * 16;
        const int row = o >> 7;
        const int c   = ((o >> 4) & 7) ^ (row & 7);
        gld_lds16(Btp + ((size_t)(n0 + row) * 1024 + bcol + c * 8), BsB + ob);
      }
      asm volatile("s_waitcnt vmcnt(0)" ::: "memory");
      __syncthreads();

#pragma unroll
      for (int kk = 0; kk < 2; ++kk) {
        const int lc = (lane >> 4) + kk * 4;
        f16x8 af[2], bf[4];
#pragma unroll
        for (int mi = 0; mi < 2; ++mi) {
          const int row = vw * 32 + mi * 16 + (lane & 15);
          af[mi] = *(const f16x8*)(AsB + row * 128 + ((lc ^ (row & 7)) << 4));
        }
#pragma unroll
        for (int ni = 0; ni < 4; ++ni) {
          const int row = ni * 16 + (lane & 15);
          bf[ni] = *(const f16x8*)(BsB + row * 128 + ((lc ^ (row & 7)) << 4));
        }
#pragma unroll
        for (int mi = 0; mi < 2; ++mi)
#pragma unroll
          for (int ni = 0; ni < 4; ++ni)
            acc[mi][ni] = __builtin_amdgcn_mfma_f32_16x16x32_f16(
                af[mi], bf[ni], acc[mi][ni], 0, 0, 0);
      }
      __syncthreads();
    }

    float* Cz = Tp + (size_t)z * 2048 * 1024;
#pragma unroll
    for (int mi = 0; mi < 2; ++mi) {
      const int r0 = m0 + vw * 32 + mi * 16 + ((lane >> 4) << 2);
#pragma unroll
      for (int ni = 0; ni < 4; ++ni) {
        const int cc = n0 + ni * 16 + (lane & 15);
#pragma unroll
        for (int q = 0; q < 4; ++q)
          Cz[(size_t)(r0 + q) * 1024 + cc] = acc[mi][ni][q] * 0.015625f;
      }
    }
  }
  gbar(cnt + 1);

  // ======================= P2: recur (R5, 4 passes) =======================
  {
    const float beta1 = fminf(fmaxf(beta1p[0], 0.1f), 0.9f);
    const float thr1  = fmaxf(thr1p[0], 0.1f);
    const float beta2 = fminf(fmaxf(beta2p[0], 0.1f), 0.9f);
    const size_t ZS = (size_t)2048 * 1024;
    const int h = (t & 63) * 8;

#pragma unroll
    for (int pass = 0; pass < 4; ++pass) {
      const int bs = b * 32 + pass * 8 + (t >> 6);
      const int x0 = x[bs * 2 + 0];
      const int x1 = x[bs * 2 + 1];
      const float* p0 = &Tp[(size_t)x0 * 1024 + h];
      const float* p1 = &Tp[(size_t)x1 * 1024 + 512 + h];

      float cur[8];
#pragma unroll
      for (int half = 0; half < 2; ++half) {
        f32x4 a0 = *(const f32x4*)(p0 + half * 4);
        f32x4 a1 = *(const f32x4*)(p0 + ZS + half * 4);
        f32x4 c0 = *(const f32x4*)(p1 + half * 4);
        f32x4 c1 = *(const f32x4*)(p1 + ZS + half * 4);
        f32x4 e  = *(const f32x4*)&b1[h + half * 4];
#pragma unroll
        for (int j = 0; j < 4; ++j)
          cur[half * 4 + j] = (a0[j] + a1[j]) + (c0[j] + c1[j]) + e[j];
      }

      float m[8] = {}, s[8] = {};
#pragma unroll
      for (int st = 0; st < NSTEPS; ++st) {
#pragma unroll
        for (int j = 0; j < 8; ++j) {
          float r = (m[j] > thr1) ? thr1 : 0.0f;     // reset from PREVIOUS mem
          m[j] = beta1 * m[j] + cur[j] - r;
          float sp = (m[j] > thr1) ? 1.0f : 0.0f;
          s[j] = beta2 * s[j] + sp;
        }
      }
      __align__(16) _Float16 o[8];
#pragma unroll
      for (int j = 0; j < 8; ++j) o[j] = (_Float16)s[j];
      *(uint4*)&S[(size_t)bs * 512 + h] = *(const uint4*)o;
    }
  }
  gbar(cnt + 2);

  // ======================= P3: gemm2 256x256 FM8/FN4 =======================
  // out = S @ W2T^T + cb*b2. 8 waves (2M x 4N), per-wave 128x64.
  // 2-deep LDS ring (2 x 64KB); stage T(t+1) inside compute phases of T(t).
  {
    const int wm = wave >> 2;
    const int wn = wave & 3;
    const int bid = (b & 7) * 32 + (b >> 3);   // XCD swizzle
    const int m0 = (bid >> 3) * 256;           // 32 m-tiles
    const int n0 = (bid & 7) * 256;            // 8 n-tiles

    f32x4 acc[8][4] = {};

    auto stage = [&](int tile, int r) {
      const int k0  = tile * 64;
      char* slot    = lds + (tile & 1) * 65536;
      const int ob  = (r & 3) * 8192 + wave * 1024;
      const int o   = ob + lane * 16;
      const int row = o >> 7;
      const int c   = ((o >> 4) & 7) ^ (row & 7);
      if (r < 4)
        gld_lds16(S   + ((size_t)(m0 + row) * 512 + k0 + c * 8), slot + ob);
      else
        gld_lds16(W2T + ((size_t)(n0 + row) * 512 + k0 + c * 8), slot + 32768 + ob);
    };

    // prologue: stage tile 0
#pragma unroll
    for (int r = 0; r < 8; ++r) stage(0, r);
    asm volatile("s_waitcnt vmcnt(0)" ::: "memory");
    __syncthreads();

    f16x8 bf[4][2];
    for (int tt = 0; tt < 8; ++tt) {
      const char* lb = lds + (tt & 1) * 65536;
      const bool pf = (tt < 7);

      // phase 0: B frags + A rows 0-3; stage rounds 0-3 of next tile
#pragma unroll
      for (int ni = 0; ni < 4; ++ni) {
        const int row = wn * 64 + ni * 16 + (lane & 15);
#pragma unroll
        for (int kk = 0; kk < 2; ++kk) {
          const int lc = (lane >> 4) + kk * 4;
          bf[ni][kk] = *(const f16x8*)(lb + 32768 + row * 128 + ((lc ^ (row & 7)) << 4));
        }
      }
      f16x8 af[4][2];
#pragma unroll
      for (int mi = 0; mi < 4; ++mi) {
        const int row = wm * 128 + mi * 16 + (lane & 15);
#pragma unroll
        for (int kk = 0; kk < 2; ++kk) {
          const int lc = (lane >> 4) + kk * 4;
          af[mi][kk] = *(const f16x8*)(lb + row * 128 + ((lc ^ (row & 7)) << 4));
        }
      }
      if (pf) { stage(tt + 1, 0); stage(tt + 1, 1); stage(tt + 1, 2); stage(tt + 1, 3); }
      __builtin_amdgcn_s_setprio(1);
#pragma unroll
      for (int kk = 0; kk < 2; ++kk)
#pragma unroll
        for (int mi = 0; mi < 4; ++mi)
#pragma unroll
          for (int ni = 0; ni < 4; ++ni)
            acc[mi][ni] = __builtin_amdgcn_mfma_f32_16x16x32_f16(
                af[mi][kk], bf[ni][kk], acc[mi][ni], 0, 0, 0);
      __builtin_amdgcn_s_setprio(0);

      // phase 1: A rows 4-7; stage rounds 4-7 of next tile
#pragma unroll
      for (int mi = 0; mi < 4; ++mi) {
        const int row = wm * 128 + 64 + mi * 16 + (lane & 15);
#pragma unroll
        for (int kk = 0; kk < 2; ++kk) {
          const int lc = (lane >> 4) + kk * 4;
          af[mi][kk] = *(const f16x8*)(lb + row * 128 + ((lc ^ (row & 7)) << 4));
        }
      }
      if (pf) { stage(tt + 1, 4); stage(tt + 1, 5); stage(tt + 1, 6); stage(tt + 1, 7); }
      __builtin_amdgcn_s_setprio(1);
#pragma unroll
      for (int kk = 0; kk < 2; ++kk)
#pragma unroll
        for (int mi = 0; mi < 4; ++mi)
#pragma unroll
          for (int ni = 0; ni < 4; ++ni)
            acc[4 + mi][ni] = __builtin_amdgcn_mfma_f32_16x16x32_f16(
                af[mi][kk], bf[ni][kk], acc[4 + mi][ni], 0, 0, 0);
      __builtin_amdgcn_s_setprio(0);

      asm volatile("s_waitcnt vmcnt(0)" ::: "memory");
      __syncthreads();
    }

    const float beta2 = fminf(fmaxf(beta2p[0], 0.1f), 0.9f);
    float cb = 0.0f;
    for (int i = 0; i < NSTEPS; ++i) cb = beta2 * cb + 1.0f;

#pragma unroll
    for (int a = 0; a < 8; ++a) {
      const int r0 = m0 + wm * 128 + (a >> 2) * 64 + (a & 3) * 16 + ((lane >> 4) << 2);
#pragma unroll
      for (int ni = 0; ni < 4; ++ni) {
        const int cc = n0 + wn * 64 + ni * 16 + (lane & 15);
        const float bv = cb * b2[cc];
#pragma unroll
        for (int q = 0; q < 4; ++q)
          out[(size_t)(r0 + q) * 2048 + cc] = acc[a][ni][q] + bv;
      }
    }
  }
}

// ---------------------------------------------------------------------------
extern "C" void kernel_launch(void* const* d_in, const int* in_sizes, int n_in,
                              void* d_out, int out_size, void* d_ws, size_t ws_size,
                              hipStream_t stream) {
  const int*   x     = (const int*)  d_in[0];
  const float* embed = (const float*)d_in[1];
  const float* W1    = (const float*)d_in[2];
  const float* b1    = (const float*)d_in[3];
  const float* W2    = (const float*)d_in[4];
  const float* b2    = (const float*)d_in[5];
  const float* beta1 = (const float*)d_in[6];
  const float* thr1  = (const float*)d_in[7];
  const float* beta2 = (const float*)d_in[8];
  // d_in[9] = thr2: clipped but unused by the output
  float* out = (float*)d_out;

  char* ws = (char*)d_ws;
  float*    Tp  = (float*)   ws;                   // 16 MB [2][2048][1024]
  _Float16* Ap  = (_Float16*)(ws + (16u << 20));   //  4 MB [2048][1024]
  _Float16* Btp = (_Float16*)(ws + (20u << 20));   //  2 MB [1024][1024]
  _Float16* W2T = (_Float16*)(ws + (22u << 20));   //  2 MB [2048][512]
  _Float16* S   = (_Float16*)(ws + (24u << 20));   //  8 MB [8192][512]
  unsigned* cnt = (unsigned*)(ws + (32u << 20));   //  32 B barrier counters

  init_kernel<<<dim3(1), 64, 0, stream>>>(cnt);
  mega_kernel<<<dim3(256), 512, 0, stream>>>(
      x, embed, W1, b1, W2, b2, beta1, thr1, beta2,
      Ap, Btp, W2T, Tp, S, cnt, out);
}

// Round 8
// 103.299 us; speedup vs baseline: 1.4231x; 1.4231x over previous
//
#include <hip/hip_runtime.h>
#include <hip/hip_bf16.h>
#include <stdint.h>

typedef float    f32x4 __attribute__((ext_vector_type(4)));
typedef _Float16 f16x4 __attribute__((ext_vector_type(4)));
typedef _Float16 f16x8 __attribute__((ext_vector_type(8)));

#define NSTEPS 15

// ---------------------------------------------------------------------------
// Fused prep kernel, block-range dispatch:
//   [0,1024)    split_e : embed [2048][512] f32 -> Ap [2048][1024] f16 = [e0|e1]
//   [1024,1152) w1t     : W1 [1024][512] f32 -> Btp [1024][1024] f16 (T, 64x, split)
//   [1152,1408) w2t     : W2 [512][2048] f32 -> W2T [2048][512] f16 (T)
//   [1408,1416) bias2   : bias2s[n] = (sum beta2^k) * b2[n]
// ---------------------------------------------------------------------------
__global__ __launch_bounds__(256) void prep_kernel(
    const float* __restrict__ embed, const float* __restrict__ W1,
    const float* __restrict__ W2, const float* __restrict__ b2,
    const float* __restrict__ beta2p,
    _Float16* __restrict__ Ap, _Float16* __restrict__ Btp,
    _Float16* __restrict__ W2T, float* __restrict__ bias2s)
{
  __shared__ _Float16 sh[2][64][72];
  const int b = blockIdx.x;
  const int t = threadIdx.x;

  if (b < 1024) {                       // ---- split_e (Dekker two-way split)
    const int i  = b * 256 + t;
    const int m  = i >> 7;
    const int k4 = (i & 127) * 4;
    f32x4 v = *(const f32x4*)&embed[(size_t)m * 512 + k4];
    f16x4 h0, h1;
#pragma unroll
    for (int j = 0; j < 4; ++j) {
      h0[j] = (_Float16)v[j];
      h1[j] = (_Float16)(v[j] - (float)h0[j]);
    }
    _Float16* r = Ap + (size_t)m * 1024 + k4;
    *(f16x4*)(r)       = h0;
    *(f16x4*)(r + 512) = h1;
  } else if (b < 1152) {                // ---- w1t_split (transpose + 64x + split)
    const int idx = b - 1024;
    const int n0 = (idx & 7) * 64;
    const int k0 = ((idx >> 3) & 7) * 64;
    const int z  = idx >> 6;
    const int kk = t >> 4;
    const int n4 = (t & 15) * 4;
#pragma unroll
    for (int i = 0; i < 4; ++i) {
      f32x4 v = *(const f32x4*)&W1[(size_t)(z * 512 + k0 + kk + i * 16) * 512 + n0 + n4];
#pragma unroll
      for (int j = 0; j < 4; ++j) {
        float s = v[j] * 64.0f;         // exact pow2 scale
        _Float16 hi = (_Float16)s;
        sh[0][n4 + j][kk + i * 16] = hi;
        sh[1][n4 + j][kk + i * 16] = (_Float16)(s - (float)hi);
      }
    }
    __syncthreads();
#pragma unroll
    for (int i = 0; i < 2; ++i) {
      const int nn = (t >> 3) + i * 32;
      const int k8 = (t & 7) * 8;
      _Float16* r = Btp + (size_t)(z * 512 + n0 + nn) * 1024 + k0 + k8;
      *(uint4*)(r)       = *(const uint4*)&sh[0][nn][k8];
      *(uint4*)(r + 512) = *(const uint4*)&sh[1][nn][k8];
    }
  } else if (b < 1408) {                // ---- w2t (transpose + f16 convert)
    const int idx = b - 1152;
    const int n0 = (idx & 31) * 64;
    const int k0 = (idx >> 5) * 64;
    const int kk = t >> 4;
    const int n4 = (t & 15) * 4;
#pragma unroll
    for (int i = 0; i < 4; ++i) {
      f32x4 v = *(const f32x4*)&W2[(size_t)(k0 + kk + i * 16) * 2048 + n0 + n4];
#pragma unroll
      for (int j = 0; j < 4; ++j) sh[0][n4 + j][kk + i * 16] = (_Float16)v[j];
    }
    __syncthreads();
#pragma unroll
    for (int i = 0; i < 2; ++i) {
      const int nn = (t >> 3) + i * 32;
      const int k8 = (t & 7) * 8;
      *(uint4*)&W2T[(size_t)(n0 + nn) * 512 + k0 + k8] = *(const uint4*)&sh[0][nn][k8];
    }
  } else {                              // ---- bias2
    const float beta2 = fminf(fmaxf(beta2p[0], 0.1f), 0.9f);
    float cb = 0.0f;
    for (int i = 0; i < NSTEPS; ++i) cb = beta2 * cb + 1.0f;
    const int n = (b - 1408) * 256 + t;
    if (n < 2048) bias2s[n] = cb * b2[n];
  }
}

// ---------------------------------------------------------------------------
__device__ __forceinline__ void gld_lds16(const void* g, void* l) {
  __builtin_amdgcn_global_load_lds(
      (const __attribute__((address_space(1))) uint32_t*)g,
      (__attribute__((address_space(3))) uint32_t*)l, 16, 0, 0);
}

// ---------------------------------------------------------------------------
// gemm1: Tp[z] = (1/64) * Ap @ Btp^T over virtual K-range [z*768,(z+1)*768)
// Virtual K=1536 = [e0w0 | e1w0 | e0w1] resolved via column maps.
// 128x64 tile, 4x1 waves, FM=2, FN=4. Grid (256, 2) -> 2 blocks/CU.
// ---------------------------------------------------------------------------
__global__ __launch_bounds__(256) void gemm1_kernel(
    const _Float16* __restrict__ Ap,   // [2048][1024]
    const _Float16* __restrict__ Btp,  // [1024][1024]
    float* __restrict__ Tp)            // [2][2048][1024]
{
  __shared__ __align__(16) char lds[(128 + 64) * 128];
  char* AsB = lds;              // 128 rows x 128B, XOR-swizzled 16B chunks
  char* BsB = lds + 128 * 128;  //  64 rows x 128B

  const int t    = threadIdx.x;
  const int lane = t & 63;
  const int wave = t >> 6;      // wm = wave (4x1), wn = 0
  const int z    = blockIdx.y;

  int bid = blockIdx.x;
  bid = (bid & 7) * 32 + (bid >> 3);   // XCD swizzle (256 % 8 == 0)
  const int m0 = (bid >> 4) * 128;     // 16 m-tiles
  const int n0 = (bid & 15) * 64;      // 16 n-tiles

  f32x4 acc[2][4] = {};

  for (int kt = 0; kt < 12; ++kt) {
    const int k0   = z * 768 + kt * 64;
    const int acol = (k0 < 1024) ? k0 : k0 - 1024;
    const int bcol = (k0 < 1024) ? (k0 & 511) : k0 - 512;
#pragma unroll
    for (int i = 0; i < 4; ++i) {      // A: 128 rows
      const int ob  = i * 4096 + wave * 1024;
      const int o   = ob + lane * 16;
      const int row = o >> 7;
      const int c   = ((o >> 4) & 7) ^ (row & 7);
      gld_lds16(Ap + ((size_t)(m0 + row) * 1024 + acol + c * 8), AsB + ob);
    }
#pragma unroll
    for (int i = 0; i < 2; ++i) {      // B: 64 rows
      const int ob  = i * 4096 + wave * 1024;
      const int o   = ob + lane * 16;
      const int row = o >> 7;
      const int c   = ((o >> 4) & 7) ^ (row & 7);
      gld_lds16(Btp + ((size_t)(n0 + row) * 1024 + bcol + c * 8), BsB + ob);
    }
    asm volatile("s_waitcnt vmcnt(0)" ::: "memory");
    __syncthreads();

#pragma unroll
    for (int kk = 0; kk < 2; ++kk) {
      const int lc = (lane >> 4) + kk * 4;
      f16x8 af[2], bf[4];
#pragma unroll
      for (int mi = 0; mi < 2; ++mi) {
        const int row = wave * 32 + mi * 16 + (lane & 15);
        af[mi] = *(const f16x8*)(AsB + row * 128 + ((lc ^ (row & 7)) << 4));
      }
#pragma unroll
      for (int ni = 0; ni < 4; ++ni) {
        const int row = ni * 16 + (lane & 15);
        bf[ni] = *(const f16x8*)(BsB + row * 128 + ((lc ^ (row & 7)) << 4));
      }
#pragma unroll
      for (int mi = 0; mi < 2; ++mi)
#pragma unroll
        for (int ni = 0; ni < 4; ++ni)
          acc[mi][ni] = __builtin_amdgcn_mfma_f32_16x16x32_f16(
              af[mi], bf[ni], acc[mi][ni], 0, 0, 0);
    }
    __syncthreads();
  }

  float* Cz = Tp + (size_t)z * 2048 * 1024;
#pragma unroll
  for (int mi = 0; mi < 2; ++mi) {
    const int r0 = m0 + wave * 32 + mi * 16 + ((lane >> 4) << 2);
#pragma unroll
    for (int ni = 0; ni < 4; ++ni) {
      const int cc = n0 + ni * 16 + (lane & 15);
#pragma unroll
      for (int q = 0; q < 4; ++q)
        Cz[(size_t)(r0 + q) * 1024 + cc] = acc[mi][ni][q] * 0.015625f;
    }
  }
}

// ---------------------------------------------------------------------------
// Per-element 15-step LIF recurrence -> weighted spike sums S [8192][512] f16
// ---------------------------------------------------------------------------
__global__ __launch_bounds__(256) void recur_kernel(
    const int* __restrict__ x,        // [8192][2]
    const float* __restrict__ Tp,     // [2][2048][1024]
    const float* __restrict__ b1,     // [512]
    const float* __restrict__ beta1p, const float* __restrict__ thr1p,
    const float* __restrict__ beta2p,
    _Float16* __restrict__ S)         // [8192][512]
{
  const float beta1 = fminf(fmaxf(beta1p[0], 0.1f), 0.9f);
  const float thr1  = fmaxf(thr1p[0], 0.1f);
  const float beta2 = fminf(fmaxf(beta2p[0], 0.1f), 0.9f);
  const size_t ZS = (size_t)2048 * 1024;

  const int t = threadIdx.x;
  const int b = blockIdx.x * 4 + (t >> 6);
  const int h = (t & 63) * 8;
  const int x0 = x[b * 2 + 0];
  const int x1 = x[b * 2 + 1];

  const float* p00 = &Tp[(size_t)x0 * 1024 + h];
  const float* p01 = &Tp[(size_t)x1 * 1024 + 512 + h];

  float cur[8];
#pragma unroll
  for (int half = 0; half < 2; ++half) {
    f32x4 a0 = *(const f32x4*)(p00 + half * 4);
    f32x4 a1 = *(const f32x4*)(p00 + ZS + half * 4);
    f32x4 c0 = *(const f32x4*)(p01 + half * 4);
    f32x4 c1 = *(const f32x4*)(p01 + ZS + half * 4);
    f32x4 e  = *(const f32x4*)&b1[h + half * 4];
#pragma unroll
    for (int j = 0; j < 4; ++j)
      cur[half * 4 + j] = (a0[j] + a1[j]) + (c0[j] + c1[j]) + e[j];
  }

  float m[8] = {}, s[8] = {};
#pragma unroll
  for (int st = 0; st < NSTEPS; ++st) {
#pragma unroll
    for (int j = 0; j < 8; ++j) {
      // reset uses PREVIOUS mem; spike uses UPDATED mem (snntorch Leaky, subtract)
      float r = (m[j] > thr1) ? thr1 : 0.0f;
      m[j] = beta1 * m[j] + cur[j] - r;
      float sp = (m[j] > thr1) ? 1.0f : 0.0f;
      s[j] = beta2 * s[j] + sp;   // S = sum_t beta2^{15-t} spk_t
    }
  }

  __align__(16) _Float16 o[8];
#pragma unroll
  for (int j = 0; j < 8; ++j) o[j] = (_Float16)s[j];
  *(uint4*)&S[(size_t)b * 512 + h] = *(const uint4*)o;
}

// ---------------------------------------------------------------------------
// gemm2 (deep-pipelined): out[8192][2048] = S @ W2T^T + bias2s
// 256x128 tile, BK=64, 8 waves (2M x 4N), 3-deep LDS ring, counted vmcnt.
// ---------------------------------------------------------------------------
__device__ __forceinline__ void g2_round(
    const _Float16* __restrict__ A, const _Float16* __restrict__ Bt,
    char* lds, int m0, int n0, int wave, int lane, int tile, int r)
{
  const int k0 = tile * 64;
  char* lb = lds + (tile % 3) * 49152;
  if (r < 4) {                       // A rounds: 256 rows x 128B
    const int ob  = r * 8192 + wave * 1024;
    const int o   = ob + lane * 16;
    const int row = o >> 7;
    const int c   = ((o >> 4) & 7) ^ (row & 7);
    gld_lds16(A + ((size_t)(m0 + row) * 512 + k0 + c * 8), lb + ob);
  } else {                           // B rounds: 128 rows x 128B
    const int ob  = (r - 4) * 8192 + wave * 1024;
    const int o   = ob + lane * 16;
    const int row = o >> 7;
    const int c   = ((o >> 4) & 7) ^ (row & 7);
    gld_lds16(Bt + ((size_t)(n0 + row) * 512 + k0 + c * 8), lb + 32768 + ob);
  }
}

template<int QA>
__device__ __forceinline__ void g2_mfma16(
    f32x4 (&acc)[8][2], const f16x8 (&af)[4][2], const f16x8 (&bf)[2][2])
{
#pragma unroll
  for (int kk = 0; kk < 2; ++kk)
#pragma unroll
    for (int mi = 0; mi < 4; ++mi)
#pragma unroll
      for (int ni = 0; ni < 2; ++ni)
        acc[QA * 4 + mi][ni] = __builtin_amdgcn_mfma_f32_16x16x32_f16(
            af[mi][kk], bf[ni][kk], acc[QA * 4 + mi][ni], 0, 0, 0);
}

template<int QA>
__device__ __forceinline__ void g2_lda(
    f16x8 (&af)[4][2], const char* lb, int wm, int lane)
{
#pragma unroll
  for (int mi = 0; mi < 4; ++mi) {
    const int row = wm * 128 + QA * 64 + mi * 16 + (lane & 15);
#pragma unroll
    for (int kk = 0; kk < 2; ++kk) {
      const int lc = (lane >> 4) + kk * 4;
      af[mi][kk] = *(const f16x8*)(lb + row * 128 + ((lc ^ (row & 7)) << 4));
    }
  }
}

__device__ __forceinline__ void g2_ldb(
    f16x8 (&bf)[2][2], const char* lb, int wn, int lane)
{
#pragma unroll
  for (int ni = 0; ni < 2; ++ni) {
    const int row = wn * 32 + ni * 16 + (lane & 15);
#pragma unroll
    for (int kk = 0; kk < 2; ++kk) {
      const int lc = (lane >> 4) + kk * 4;
      bf[ni][kk] = *(const f16x8*)(lb + 32768 + row * 128 + ((lc ^ (row & 7)) << 4));
    }
  }
}

__global__ __launch_bounds__(512, 2) void gemm2_pipe_kernel(
    const _Float16* __restrict__ A,    // S   [8192][512]
    const _Float16* __restrict__ Bt,   // W2T [2048][512]
    const float* __restrict__ bias,    // [2048]
    float* __restrict__ C)             // [8192][2048]
{
  __shared__ __align__(16) char lds[3 * 49152];   // 144 KB

  const int t    = threadIdx.x;
  const int lane = t & 63;
  const int wave = t >> 6;
  const int wm   = wave >> 2;   // 0..1
  const int wn   = wave & 3;    // 0..3

  int bid = blockIdx.x;
  bid = (bid & 7) * 64 + (bid >> 3);   // XCD swizzle (512 % 8 == 0)
  const int m0 = (bid >> 4) * 256;     // 32 m-tiles
  const int n0 = (bid & 15) * 128;     // 16 n-tiles

  f32x4 acc[8][2] = {};
  f16x8 af[4][2], bf[2][2];

  // prologue: T0, T1 fully staged; vmcnt(6) -> T0 resident
#pragma unroll
  for (int r = 0; r < 6; ++r) g2_round(A, Bt, lds, m0, n0, wave, lane, 0, r);
#pragma unroll
  for (int r = 0; r < 6; ++r) g2_round(A, Bt, lds, m0, n0, wave, lane, 1, r);
  asm volatile("s_waitcnt vmcnt(6)" ::: "memory");
  __builtin_amdgcn_s_barrier();

  for (int tt = 0; tt < 8; ++tt) {
    const char* lb = lds + (tt % 3) * 49152;
    const bool pf = (tt + 2 < 8);

    g2_lda<0>(af, lb, wm, lane);
    g2_ldb(bf, lb, wn, lane);
    if (pf) {
      g2_round(A, Bt, lds, m0, n0, wave, lane, tt + 2, 0);
      g2_round(A, Bt, lds, m0, n0, wave, lane, tt + 2, 1);
      g2_round(A, Bt, lds, m0, n0, wave, lane, tt + 2, 2);
    }
    __builtin_amdgcn_s_barrier();
    asm volatile("s_waitcnt lgkmcnt(0)" ::: "memory");
    __builtin_amdgcn_s_setprio(1);
    g2_mfma16<0>(acc, af, bf);
    __builtin_amdgcn_s_setprio(0);
    __builtin_amdgcn_s_barrier();

    g2_lda<1>(af, lb, wm, lane);
    if (pf) {
      g2_round(A, Bt, lds, m0, n0, wave, lane, tt + 2, 3);
      g2_round(A, Bt, lds, m0, n0, wave, lane, tt + 2, 4);
      g2_round(A, Bt, lds, m0, n0, wave, lane, tt + 2, 5);
    }
    __builtin_amdgcn_s_barrier();
    asm volatile("s_waitcnt lgkmcnt(0)" ::: "memory");
    __builtin_amdgcn_s_setprio(1);
    g2_mfma16<1>(acc, af, bf);
    __builtin_amdgcn_s_setprio(0);
    asm volatile("s_waitcnt vmcnt(6)" ::: "memory");
    __builtin_amdgcn_s_barrier();
  }

  // epilogue: C/D layout col=lane&15, row=(lane>>4)*4+reg
#pragma unroll
  for (int a = 0; a < 8; ++a) {
    const int r0 = m0 + wm * 128 + a * 16 + ((lane >> 4) << 2);
#pragma unroll
    for (int ni = 0; ni < 2; ++ni) {
      const int cc = n0 + wn * 32 + ni * 16 + (lane & 15);
      const float bv = bias[cc];
#pragma unroll
      for (int q = 0; q < 4; ++q)
        C[(size_t)(r0 + q) * 2048 + cc] = acc[a][ni][q] + bv;
    }
  }
}

// ---------------------------------------------------------------------------
// MEASUREMENT ROUND: exact R5-best graph + 3 extra (idempotent) recur launches.
// dur' - 65.2 = 3 * (t_recur + node_overhead). recur is a pure deterministic
// function of (x, Tp, b1, params) -> S, so re-running it is output-invariant.
// ---------------------------------------------------------------------------
extern "C" void kernel_launch(void* const* d_in, const int* in_sizes, int n_in,
                              void* d_out, int out_size, void* d_ws, size_t ws_size,
                              hipStream_t stream) {
  const int*   x     = (const int*)  d_in[0];
  const float* embed = (const float*)d_in[1];
  const float* W1    = (const float*)d_in[2];
  const float* b1    = (const float*)d_in[3];
  const float* W2    = (const float*)d_in[4];
  const float* b2    = (const float*)d_in[5];
  const float* beta1 = (const float*)d_in[6];
  const float* thr1  = (const float*)d_in[7];
  const float* beta2 = (const float*)d_in[8];
  // d_in[9] = thr2: clipped but unused by the output
  float* out = (float*)d_out;

  char* ws = (char*)d_ws;
  float*    Tp     = (float*)   ws;                     // 16 MB [2][2048][1024]
  _Float16* Ap     = (_Float16*)(ws + (16u << 20));     //  4 MB [2048][1024]
  _Float16* Btp    = (_Float16*)(ws + (20u << 20));     //  2 MB [1024][1024]
  _Float16* W2T    = (_Float16*)(ws + (22u << 20));     //  2 MB [2048][512]
  _Float16* S      = (_Float16*)(ws + (24u << 20));     //  8 MB [8192][512]
  float*    bias2s = (float*)   (ws + (32u << 20));     //  8 KB

  prep_kernel<<<dim3(1416), 256, 0, stream>>>(embed, W1, W2, b2, beta2,
                                              Ap, Btp, W2T, bias2s);

  gemm1_kernel<<<dim3(256, 2), 256, 0, stream>>>(Ap, Btp, Tp);

  // recur x4: 1 real + 3 timing probes (idempotent)
  recur_kernel<<<dim3(2048), 256, 0, stream>>>(x, Tp, b1, beta1, thr1, beta2, S);
  recur_kernel<<<dim3(2048), 256, 0, stream>>>(x, Tp, b1, beta1, thr1, beta2, S);
  recur_kernel<<<dim3(2048), 256, 0, stream>>>(x, Tp, b1, beta1, thr1, beta2, S);
  recur_kernel<<<dim3(2048), 256, 0, stream>>>(x, Tp, b1, beta1, thr1, beta2, S);

  gemm2_pipe_kernel<<<dim3(512), 512, 0, stream>>>(S, W2T, bias2s, out);
}

// Round 9
// 67.612 us; speedup vs baseline: 2.1743x; 1.5278x over previous
//
#include <hip/hip_runtime.h>
#include <hip/hip_bf16.h>
#include <stdint.h>

typedef float    f32x4 __attribute__((ext_vector_type(4)));
typedef _Float16 f16x4 __attribute__((ext_vector_type(4)));
typedef _Float16 f16x8 __attribute__((ext_vector_type(8)));

#define NSTEPS 15

// ---------------------------------------------------------------------------
// Fused prep kernel, block-range dispatch:
//   [0,1024)    split_e : embed [2048][512] f32 -> Ap [2048][1024] f16 = [e0|e1]
//   [1024,1152) w1t     : W1 [1024][512] f32 -> Btp [1024][1024] f16 (T, 64x, split)
//   [1152,1408) w2t     : W2 [512][2048] f32 -> W2T [2048][512] f16 (T)
// ---------------------------------------------------------------------------
__global__ __launch_bounds__(256) void prep_kernel(
    const float* __restrict__ embed, const float* __restrict__ W1,
    const float* __restrict__ W2,
    _Float16* __restrict__ Ap, _Float16* __restrict__ Btp,
    _Float16* __restrict__ W2T)
{
  __shared__ _Float16 sh[2][64][72];
  const int b = blockIdx.x;
  const int t = threadIdx.x;

  if (b < 1024) {                       // ---- split_e (Dekker two-way split)
    const int i  = b * 256 + t;
    const int m  = i >> 7;
    const int k4 = (i & 127) * 4;
    f32x4 v = *(const f32x4*)&embed[(size_t)m * 512 + k4];
    f16x4 h0, h1;
#pragma unroll
    for (int j = 0; j < 4; ++j) {
      h0[j] = (_Float16)v[j];
      h1[j] = (_Float16)(v[j] - (float)h0[j]);
    }
    _Float16* r = Ap + (size_t)m * 1024 + k4;
    *(f16x4*)(r)       = h0;
    *(f16x4*)(r + 512) = h1;
  } else if (b < 1152) {                // ---- w1t_split (transpose + 64x + split)
    const int idx = b - 1024;
    const int n0 = (idx & 7) * 64;
    const int k0 = ((idx >> 3) & 7) * 64;
    const int z  = idx >> 6;
    const int kk = t >> 4;
    const int n4 = (t & 15) * 4;
#pragma unroll
    for (int i = 0; i < 4; ++i) {
      f32x4 v = *(const f32x4*)&W1[(size_t)(z * 512 + k0 + kk + i * 16) * 512 + n0 + n4];
#pragma unroll
      for (int j = 0; j < 4; ++j) {
        float s = v[j] * 64.0f;         // exact pow2 scale
        _Float16 hi = (_Float16)s;
        sh[0][n4 + j][kk + i * 16] = hi;
        sh[1][n4 + j][kk + i * 16] = (_Float16)(s - (float)hi);
      }
    }
    __syncthreads();
#pragma unroll
    for (int i = 0; i < 2; ++i) {
      const int nn = (t >> 3) + i * 32;
      const int k8 = (t & 7) * 8;
      _Float16* r = Btp + (size_t)(z * 512 + n0 + nn) * 1024 + k0 + k8;
      *(uint4*)(r)       = *(const uint4*)&sh[0][nn][k8];
      *(uint4*)(r + 512) = *(const uint4*)&sh[1][nn][k8];
    }
  } else {                              // ---- w2t (transpose + f16 convert)
    const int idx = b - 1152;
    const int n0 = (idx & 31) * 64;
    const int k0 = (idx >> 5) * 64;
    const int kk = t >> 4;
    const int n4 = (t & 15) * 4;
#pragma unroll
    for (int i = 0; i < 4; ++i) {
      f32x4 v = *(const f32x4*)&W2[(size_t)(k0 + kk + i * 16) * 2048 + n0 + n4];
#pragma unroll
      for (int j = 0; j < 4; ++j) sh[0][n4 + j][kk + i * 16] = (_Float16)v[j];
    }
    __syncthreads();
#pragma unroll
    for (int i = 0; i < 2; ++i) {
      const int nn = (t >> 3) + i * 32;
      const int k8 = (t & 7) * 8;
      *(uint4*)&W2T[(size_t)(n0 + nn) * 512 + k0 + k8] = *(const uint4*)&sh[0][nn][k8];
    }
  }
}

// ---------------------------------------------------------------------------
__device__ __forceinline__ void gld_lds16(const void* g, void* l) {
  __builtin_amdgcn_global_load_lds(
      (const __attribute__((address_space(1))) uint32_t*)g,
      (__attribute__((address_space(3))) uint32_t*)l, 16, 0, 0);
}

// ---------------------------------------------------------------------------
// gemm1 (64x64 full-K): T[2048][1024] = (1/64) * Ap @ Btp^T, virtual K=1536
//   = [e0w0 | e1w0 | e0w1]; acol(vk) = vk<1024 ? vk : vk-1024,
//                           bcol(vk) = vk<1024 ? vk&511 : vk-512.
// T's col space is z*512+h (both W1-halves) -> single pre-summed table.
// Grid 32x16 = 512 blocks -> 2 blocks/CU. 4 waves (2x2), per-wave 32x32.
// ---------------------------------------------------------------------------
__global__ __launch_bounds__(256) void gemm1_kernel(
    const _Float16* __restrict__ Ap,   // [2048][1024]
    const _Float16* __restrict__ Btp,  // [1024][1024]
    float* __restrict__ T)             // [2048][1024]
{
  __shared__ __align__(16) char lds[16384];
  char* AsB = lds;          // 64 rows x 128B, XOR-swizzled 16B chunks
  char* BsB = lds + 8192;   // 64 rows x 128B

  const int t    = threadIdx.x;
  const int lane = t & 63;
  const int wave = t >> 6;
  const int wm   = wave >> 1;
  const int wn   = wave & 1;

  int bid = blockIdx.x;
  bid = (bid & 7) * 64 + (bid >> 3);   // XCD swizzle (512 % 8 == 0)
  const int m0 = (bid >> 4) * 64;      // 32 m-tiles
  const int n0 = (bid & 15) * 64;      // 16 n-tiles

  f32x4 acc[2][2] = {};

  for (int kt = 0; kt < 24; ++kt) {
    const int vk0  = kt * 64;
    const int acol = (vk0 < 1024) ? vk0 : vk0 - 1024;
    const int bcol = (vk0 < 1024) ? (vk0 & 511) : vk0 - 512;
#pragma unroll
    for (int i = 0; i < 2; ++i) {      // A: 8 chunks, 2 per wave
      const int ob  = (wave * 2 + i) * 1024;
      const int o   = ob + lane * 16;
      const int row = o >> 7;
      const int c   = ((o >> 4) & 7) ^ (row & 7);
      gld_lds16(Ap + ((size_t)(m0 + row) * 1024 + acol + c * 8), AsB + ob);
    }
#pragma unroll
    for (int i = 0; i < 2; ++i) {      // B: 8 chunks, 2 per wave
      const int ob  = (wave * 2 + i) * 1024;
      const int o   = ob + lane * 16;
      const int row = o >> 7;
      const int c   = ((o >> 4) & 7) ^ (row & 7);
      gld_lds16(Btp + ((size_t)(n0 + row) * 1024 + bcol + c * 8), BsB + ob);
    }
    asm volatile("s_waitcnt vmcnt(0)" ::: "memory");
    __syncthreads();

#pragma unroll
    for (int kk = 0; kk < 2; ++kk) {
      const int lc = (lane >> 4) + kk * 4;
      f16x8 af[2], bf[2];
#pragma unroll
      for (int mi = 0; mi < 2; ++mi) {
        const int row = wm * 32 + mi * 16 + (lane & 15);
        af[mi] = *(const f16x8*)(AsB + row * 128 + ((lc ^ (row & 7)) << 4));
      }
#pragma unroll
      for (int ni = 0; ni < 2; ++ni) {
        const int row = wn * 32 + ni * 16 + (lane & 15);
        bf[ni] = *(const f16x8*)(BsB + row * 128 + ((lc ^ (row & 7)) << 4));
      }
#pragma unroll
      for (int mi = 0; mi < 2; ++mi)
#pragma unroll
        for (int ni = 0; ni < 2; ++ni)
          acc[mi][ni] = __builtin_amdgcn_mfma_f32_16x16x32_f16(
              af[mi], bf[ni], acc[mi][ni], 0, 0, 0);
    }
    __syncthreads();
  }

  // epilogue: C/D layout col=lane&15, row=(lane>>4)*4+reg
#pragma unroll
  for (int mi = 0; mi < 2; ++mi) {
    const int r0 = m0 + wm * 32 + mi * 16 + ((lane >> 4) << 2);
#pragma unroll
    for (int ni = 0; ni < 2; ++ni) {
      const int cc = n0 + wn * 32 + ni * 16 + (lane & 15);
#pragma unroll
      for (int q = 0; q < 4; ++q)
        T[(size_t)(r0 + q) * 1024 + cc] = acc[mi][ni][q] * 0.015625f;
    }
  }
}

// ---------------------------------------------------------------------------
// Per-element 15-step LIF recurrence -> weighted spike sums S [8192][512] f16
// cur1 = T[x0][0:512] + T[x1][512:1024] + b1  (single pre-summed table)
// ---------------------------------------------------------------------------
__global__ __launch_bounds__(256) void recur_kernel(
    const int* __restrict__ x,        // [8192][2]
    const float* __restrict__ T,      // [2048][1024]
    const float* __restrict__ b1,     // [512]
    const float* __restrict__ beta1p, const float* __restrict__ thr1p,
    const float* __restrict__ beta2p,
    _Float16* __restrict__ S)         // [8192][512]
{
  const float beta1 = fminf(fmaxf(beta1p[0], 0.1f), 0.9f);
  const float thr1  = fmaxf(thr1p[0], 0.1f);
  const float beta2 = fminf(fmaxf(beta2p[0], 0.1f), 0.9f);

  const int t = threadIdx.x;
  const int b = blockIdx.x * 4 + (t >> 6);
  const int h = (t & 63) * 8;
  const int x0 = x[b * 2 + 0];
  const int x1 = x[b * 2 + 1];

  const float* p0 = &T[(size_t)x0 * 1024 + h];
  const float* p1 = &T[(size_t)x1 * 1024 + 512 + h];

  float cur[8];
#pragma unroll
  for (int half = 0; half < 2; ++half) {
    f32x4 a = *(const f32x4*)(p0 + half * 4);
    f32x4 c = *(const f32x4*)(p1 + half * 4);
    f32x4 e = *(const f32x4*)&b1[h + half * 4];
#pragma unroll
    for (int j = 0; j < 4; ++j)
      cur[half * 4 + j] = (a[j] + c[j]) + e[j];
  }

  float m[8] = {}, s[8] = {};
#pragma unroll
  for (int st = 0; st < NSTEPS; ++st) {
#pragma unroll
    for (int j = 0; j < 8; ++j) {
      // reset uses PREVIOUS mem; spike uses UPDATED mem (snntorch Leaky, subtract)
      float r = (m[j] > thr1) ? thr1 : 0.0f;
      m[j] = beta1 * m[j] + cur[j] - r;
      float sp = (m[j] > thr1) ? 1.0f : 0.0f;
      s[j] = beta2 * s[j] + sp;   // S = sum_t beta2^{15-t} spk_t
    }
  }

  __align__(16) _Float16 o[8];
#pragma unroll
  for (int j = 0; j < 8; ++j) o[j] = (_Float16)s[j];
  *(uint4*)&S[(size_t)b * 512 + h] = *(const uint4*)o;
}

// ---------------------------------------------------------------------------
// gemm2 (deep-pipelined): out[8192][2048] = S @ W2T^T + cb*b2
// 256x128 tile, BK=64, 8 waves (2M x 4N), 3-deep LDS ring, counted vmcnt.
// ---------------------------------------------------------------------------
__device__ __forceinline__ void g2_round(
    const _Float16* __restrict__ A, const _Float16* __restrict__ Bt,
    char* lds, int m0, int n0, int wave, int lane, int tile, int r)
{
  const int k0 = tile * 64;
  char* lb = lds + (tile % 3) * 49152;
  if (r < 4) {                       // A rounds: 256 rows x 128B
    const int ob  = r * 8192 + wave * 1024;
    const int o   = ob + lane * 16;
    const int row = o >> 7;
    const int c   = ((o >> 4) & 7) ^ (row & 7);
    gld_lds16(A + ((size_t)(m0 + row) * 512 + k0 + c * 8), lb + ob);
  } else {                           // B rounds: 128 rows x 128B
    const int ob  = (r - 4) * 8192 + wave * 1024;
    const int o   = ob + lane * 16;
    const int row = o >> 7;
    const int c   = ((o >> 4) & 7) ^ (row & 7);
    gld_lds16(Bt + ((size_t)(n0 + row) * 512 + k0 + c * 8), lb + 32768 + ob);
  }
}

template<int QA>
__device__ __forceinline__ void g2_mfma16(
    f32x4 (&acc)[8][2], const f16x8 (&af)[4][2], const f16x8 (&bf)[2][2])
{
#pragma unroll
  for (int kk = 0; kk < 2; ++kk)
#pragma unroll
    for (int mi = 0; mi < 4; ++mi)
#pragma unroll
      for (int ni = 0; ni < 2; ++ni)
        acc[QA * 4 + mi][ni] = __builtin_amdgcn_mfma_f32_16x16x32_f16(
            af[mi][kk], bf[ni][kk], acc[QA * 4 + mi][ni], 0, 0, 0);
}

template<int QA>
__device__ __forceinline__ void g2_lda(
    f16x8 (&af)[4][2], const char* lb, int wm, int lane)
{
#pragma unroll
  for (int mi = 0; mi < 4; ++mi) {
    const int row = wm * 128 + QA * 64 + mi * 16 + (lane & 15);
#pragma unroll
    for (int kk = 0; kk < 2; ++kk) {
      const int lc = (lane >> 4) + kk * 4;
      af[mi][kk] = *(const f16x8*)(lb + row * 128 + ((lc ^ (row & 7)) << 4));
    }
  }
}

__device__ __forceinline__ void g2_ldb(
    f16x8 (&bf)[2][2], const char* lb, int wn, int lane)
{
#pragma unroll
  for (int ni = 0; ni < 2; ++ni) {
    const int row = wn * 32 + ni * 16 + (lane & 15);
#pragma unroll
    for (int kk = 0; kk < 2; ++kk) {
      const int lc = (lane >> 4) + kk * 4;
      bf[ni][kk] = *(const f16x8*)(lb + 32768 + row * 128 + ((lc ^ (row & 7)) << 4));
    }
  }
}

__global__ __launch_bounds__(512, 2) void gemm2_pipe_kernel(
    const _Float16* __restrict__ A,    // S   [8192][512]
    const _Float16* __restrict__ Bt,   // W2T [2048][512]
    const float* __restrict__ b2,      // [2048]
    const float* __restrict__ beta2p,
    float* __restrict__ C)             // [8192][2048]
{
  __shared__ __align__(16) char lds[3 * 49152];   // 144 KB

  const int t    = threadIdx.x;
  const int lane = t & 63;
  const int wave = t >> 6;
  const int wm   = wave >> 2;   // 0..1
  const int wn   = wave & 3;    // 0..3

  int bid = blockIdx.x;
  bid = (bid & 7) * 64 + (bid >> 3);   // XCD swizzle (512 % 8 == 0)
  const int m0 = (bid >> 4) * 256;     // 32 m-tiles
  const int n0 = (bid & 15) * 128;     // 16 n-tiles

  f32x4 acc[8][2] = {};
  f16x8 af[4][2], bf[2][2];

  // prologue: T0, T1 fully staged; vmcnt(6) -> T0 resident
#pragma unroll
  for (int r = 0; r < 6; ++r) g2_round(A, Bt, lds, m0, n0, wave, lane, 0, r);
#pragma unroll
  for (int r = 0; r < 6; ++r) g2_round(A, Bt, lds, m0, n0, wave, lane, 1, r);
  asm volatile("s_waitcnt vmcnt(6)" ::: "memory");
  __builtin_amdgcn_s_barrier();

  for (int tt = 0; tt < 8; ++tt) {
    const char* lb = lds + (tt % 3) * 49152;
    const bool pf = (tt + 2 < 8);

    g2_lda<0>(af, lb, wm, lane);
    g2_ldb(bf, lb, wn, lane);
    if (pf) {
      g2_round(A, Bt, lds, m0, n0, wave, lane, tt + 2, 0);
      g2_round(A, Bt, lds, m0, n0, wave, lane, tt + 2, 1);
      g2_round(A, Bt, lds, m0, n0, wave, lane, tt + 2, 2);
    }
    __builtin_amdgcn_s_barrier();
    asm volatile("s_waitcnt lgkmcnt(0)" ::: "memory");
    __builtin_amdgcn_s_setprio(1);
    g2_mfma16<0>(acc, af, bf);
    __builtin_amdgcn_s_setprio(0);
    __builtin_amdgcn_s_barrier();

    g2_lda<1>(af, lb, wm, lane);
    if (pf) {
      g2_round(A, Bt, lds, m0, n0, wave, lane, tt + 2, 3);
      g2_round(A, Bt, lds, m0, n0, wave, lane, tt + 2, 4);
      g2_round(A, Bt, lds, m0, n0, wave, lane, tt + 2, 5);
    }
    __builtin_amdgcn_s_barrier();
    asm volatile("s_waitcnt lgkmcnt(0)" ::: "memory");
    __builtin_amdgcn_s_setprio(1);
    g2_mfma16<1>(acc, af, bf);
    __builtin_amdgcn_s_setprio(0);
    asm volatile("s_waitcnt vmcnt(6)" ::: "memory");
    __builtin_amdgcn_s_barrier();
  }

  // inline bias: cb = sum_{k<15} beta2^k (clamped beta2)
  const float beta2 = fminf(fmaxf(beta2p[0], 0.1f), 0.9f);
  float cb = 0.0f;
  for (int i = 0; i < NSTEPS; ++i) cb = beta2 * cb + 1.0f;

  // epilogue: C/D layout col=lane&15, row=(lane>>4)*4+reg
#pragma unroll
  for (int a = 0; a < 8; ++a) {
    const int r0 = m0 + wm * 128 + a * 16 + ((lane >> 4) << 2);
#pragma unroll
    for (int ni = 0; ni < 2; ++ni) {
      const int cc = n0 + wn * 32 + ni * 16 + (lane & 15);
      const float bv = cb * b2[cc];
#pragma unroll
      for (int q = 0; q < 4; ++q)
        C[(size_t)(r0 + q) * 2048 + cc] = acc[a][ni][q] + bv;
    }
  }
}

// ---------------------------------------------------------------------------
extern "C" void kernel_launch(void* const* d_in, const int* in_sizes, int n_in,
                              void* d_out, int out_size, void* d_ws, size_t ws_size,
                              hipStream_t stream) {
  const int*   x     = (const int*)  d_in[0];
  const float* embed = (const float*)d_in[1];
  const float* W1    = (const float*)d_in[2];
  const float* b1    = (const float*)d_in[3];
  const float* W2    = (const float*)d_in[4];
  const float* b2    = (const float*)d_in[5];
  const float* beta1 = (const float*)d_in[6];
  const float* thr1  = (const float*)d_in[7];
  const float* beta2 = (const float*)d_in[8];
  // d_in[9] = thr2: clipped but unused by the output
  float* out = (float*)d_out;

  char* ws = (char*)d_ws;
  float*    T   = (float*)   ws;                   //  8 MB [2048][1024]
  _Float16* Ap  = (_Float16*)(ws + ( 8u << 20));   //  4 MB [2048][1024]
  _Float16* Btp = (_Float16*)(ws + (12u << 20));   //  2 MB [1024][1024]
  _Float16* W2T = (_Float16*)(ws + (14u << 20));   //  2 MB [2048][512]
  _Float16* S   = (_Float16*)(ws + (16u << 20));   //  8 MB [8192][512]

  prep_kernel<<<dim3(1408), 256, 0, stream>>>(embed, W1, W2, Ap, Btp, W2T);

  // T = embed@W1 pre-summed (64x64 tile, full virtual K=1536, 512 blocks)
  gemm1_kernel<<<dim3(512), 256, 0, stream>>>(Ap, Btp, T);

  recur_kernel<<<dim3(2048), 256, 0, stream>>>(x, T, b1, beta1, thr1, beta2, S);

  // out = S @ W2 + cb*b2  (256x128 tile, 3-deep pipeline, counted vmcnt)
  gemm2_pipe_kernel<<<dim3(512), 512, 0, stream>>>(S, W2T, b2, beta2, out);
}